// Round 10
// baseline (291.269 us; speedup 1.0000x reference)
//
#include <hip/hip_runtime.h>
#include <cstdint>

#if __has_builtin(__builtin_amdgcn_exp2f)
#define EXP2F(x) __builtin_amdgcn_exp2f(x)
#else
#define EXP2F(x) exp2f(x)
#endif

typedef _Float16 half8 __attribute__((ext_vector_type(8)));
typedef float    f32x4 __attribute__((ext_vector_type(4)));

// x: (4,1024,64,512) f32; u = x[...,0:256], v = x[...,256:512]
// d = vd*16 + s (head s = d&15); head params hb = s*1024 + w
// score(m,n) = ax*dx + ay*dy - 0.5*(dx^2+dy^2); dx = (n&7)-(m&7), dy = (m>>3)-(n>>3)
// mixed[m,vd,s] = softmax_n(score).Us[n,vd,s]; out = (mixed + bias[w,m]) * v
//
// Round 9 = round 8, one lever: __launch_bounds__(512,6) to force VGPR<=85
// -> 3 WGs/CU (24 waves). CQ restructured head-sequential (head A fully,
// then head B) to cut transient register pressure so the allocation closes
// without spill. Theory: 2 WGs/CU give ~80% read-issue duty (matches the
// measured 82% of copy ceiling); 3 WGs close the gap.

#define BARRIER() do {                                        \
    asm volatile("s_waitcnt lgkmcnt(0)" ::: "memory");        \
    __builtin_amdgcn_s_barrier();                             \
} while (0)

__global__ __launch_bounds__(512, 6) void sgating_kernel(
    const float* __restrict__ x,
    const float* __restrict__ norm_w,
    const float* __restrict__ norm_b,
    const float* __restrict__ centers,
    const float* __restrict__ spreads,
    const float* __restrict__ tbias,
    float* __restrict__ out)
{
    __shared__ __align__(16) float smem[12288];   // 48 KB: Us 32K + Qm 16K
    _Float16* Us = (_Float16*)smem;
    float*    Qm = smem + 8192;

    const int t     = threadIdx.x;
    const int wv    = t >> 6;
    const int lane  = t & 63;
    const int bw    = blockIdx.x;       // b*1024 + w
    const int w_idx = bw & 1023;
    const size_t xbase = (size_t)bw * (64 * 512);
    const size_t obase = (size_t)bw * (64 * 256);

    // ---------------- Phase 1: load u + LayerNorm -> Us ----------------
    {
        const float4 w4 = *(const float4*)(norm_w + lane * 4);
        const float4 b4 = *(const float4*)(norm_b + lane * 4);
        half8 uar[4];
#pragma unroll
        for (int r = 0; r < 8; ++r) {
            const int n = r * 8 + wv;
            const float4 u = *(const float4*)(x + xbase + (size_t)n * 512 + lane * 4);
            float s  = u.x + u.y + u.z + u.w;
            float sq = u.x*u.x + u.y*u.y + u.z*u.z + u.w*u.w;
#pragma unroll
            for (int off = 1; off < 64; off <<= 1) {
                s  += __shfl_xor(s, off);
                sq += __shfl_xor(sq, off);
            }
            const float mean = s * (1.0f/256.0f);
            const float var  = sq * (1.0f/256.0f) - mean*mean;
            const float rstd = rsqrtf(var + 1e-5f);
            uar[0][r] = (_Float16)((u.x - mean)*rstd*w4.x + b4.x);
            uar[1][r] = (_Float16)((u.y - mean)*rstd*w4.y + b4.y);
            uar[2][r] = (_Float16)((u.z - mean)*rstd*w4.z + b4.z);
            uar[3][r] = (_Float16)((u.w - mean)*rstd*w4.w + b4.w);
        }
        // uar[j][r] = value at n = r*8+wv (q = wv, j-slot = r) -> contiguous b128
#pragma unroll
        for (int j = 0; j < 4; ++j) {
            const int d  = lane * 4 + j;
            const int s  = d & 15;
            const int vd = d >> 4;
            const int qb = wv ^ (vd & 7);
            *(half8*)(Us + (s << 10) + (vd << 6) + (qb << 3)) = uar[j];
        }
    }

    // ---------------- Phase 2 setup ----------------
    const int m16 = lane & 15;
    const int g   = lane >> 4;
    const float LOG2E = 1.4426950408889634f;
    const float C2    = 0.72134752044448f;   // 0.5*log2(e)
    const float mx  = (float)(m16 & 7);
    const float myb = (float)(m16 >> 3);
    const int sA = wv, sB = wv + 8;

    float bias4[4];
#pragma unroll
    for (int nt = 0; nt < 4; ++nt)
        bias4[nt] = tbias[w_idx * 64 + nt * 16 + m16];

    float    exfA[2], exfB[2];
    _Float16 exhA[2], exhB[2];
    half8 EYA_[2], EYB_[2];     // 14-entry f16 ey tables, i -> dy = i-7+myb
    {
        const int hbA = (sA << 10) | w_idx;
        const int hbB = (sB << 10) | w_idx;
        float aq = spreads[hbA]; aq *= aq;
        const float axlA = aq * centers[2*hbA]     * LOG2E;
        const float aylA = aq * centers[2*hbA + 1] * LOG2E;
        aq = spreads[hbB]; aq *= aq;
        const float axlB = aq * centers[2*hbB]     * LOG2E;
        const float aylB = aq * centers[2*hbB + 1] * LOG2E;
#pragma unroll
        for (int kt = 0; kt < 2; ++kt) {
            const float dx = (float)(g + 4*kt) - mx;
            const float eA = EXP2F(dx * fmaf(-C2, dx, axlA));
            const float eB = EXP2F(dx * fmaf(-C2, dx, axlB));
            exfA[kt] = eA; exhA[kt] = (_Float16)eA;
            exfB[kt] = eB; exhB[kt] = (_Float16)eB;
        }
#pragma unroll
        for (int i = 0; i < 16; ++i) {
            const float dy = (float)(i - 7) + myb;
            const _Float16 eA = (i < 14) ? (_Float16)EXP2F(dy * fmaf(-C2, dy, aylA)) : (_Float16)0.f;
            const _Float16 eB = (i < 14) ? (_Float16)EXP2F(dy * fmaf(-C2, dy, aylB)) : (_Float16)0.f;
            if (i < 8) { EYA_[0][i] = eA; EYB_[0][i] = eB; }
            else       { EYA_[1][i-8] = eA; EYB_[1][i-8] = eB; }
        }
    }

// one head's quarter: acc -> softmax-normalized + bias  (low transient VGPR)
#define CQH(NT, SS, EXH, EXF, EYT, VOUT) do {                                  \
    f32x4 a_ = (f32x4){0.f,0.f,0.f,0.f};                                       \
    half8 ey8_;                                                                \
    float sy_ = 0.f;                                                           \
    _Pragma("unroll") for (int j = 0; j < 8; ++j) {                            \
        const int idx_ = 2*(NT)+7-j;                                           \
        const _Float16 e_ = (idx_ < 8) ? (EYT)[0][idx_] : (EYT)[1][idx_-8];    \
        ey8_[j] = e_; sy_ += (float)e_;                                        \
    }                                                                          \
    _Pragma("unroll") for (int kt = 0; kt < 2; ++kt) {                         \
        const int qb_ = (g + 4*kt) ^ (m16 & 7);                                \
        const half8 u_ = *(const half8*)(Us + ((SS)<<10) + (m16<<6) + (qb_<<3));\
        const _Float16 eh_ = (EXH)[kt];                                        \
        half8 w_;                                                              \
        _Pragma("unroll") for (int j = 0; j < 8; ++j) w_[j] = ey8_[j] * eh_;   \
        a_ = __builtin_amdgcn_mfma_f32_16x16x32_f16(u_, w_, a_, 0, 0, 0);      \
    }                                                                          \
    float r_ = ((EXF)[0] + (EXF)[1]) * sy_;                                    \
    r_ += __shfl_xor(r_, 16); r_ += __shfl_xor(r_, 32);                        \
    const float inv_ = 1.0f / r_;                                              \
    const float bm_ = bias4[(NT)];                                             \
    _Pragma("unroll") for (int j = 0; j < 4; ++j) (VOUT)[j] = a_[j]*inv_ + bm_;\
} while (0)

#define CQ(NT, vOutA, vOutB) do {                                              \
    CQH(NT, sA, exhA, exfA, EYA_, vOutA);                                      \
    CQH(NT, sB, exhB, exfB, EYB_, vOutB);                                      \
} while (0)

#define WRITEQ(vA_, vB_) do {                                                  \
    const int swz = (m16 & 7) << 2;                                            \
    *(f32x4*)(Qm + (m16<<8) + ((sA*16 + g*4) ^ swz)) = vA_;                    \
    *(f32x4*)(Qm + (m16<<8) + ((sB*16 + g*4) ^ swz)) = vB_;                    \
} while (0)

#define VLOAD(NT, V0, V1) do {                                                 \
    V0 = *(const f32x4*)(x + xbase + (size_t)(16*(NT)+wv)*512 + 256 + lane*4); \
    V1 = *(const f32x4*)(x + xbase + (size_t)(16*(NT)+8+wv)*512 + 256 + lane*4);\
} while (0)

#define EPI1(NT, K, VH) do {                                                   \
    const int mr  = wv + 8*(K);                                                \
    const int m   = (NT)*16 + mr;                                              \
    const int c4  = lane * 4;                                                  \
    const int vd  = c4 >> 4;                                                   \
    const int s0  = c4 & 15;                                                   \
    const int sw2 = (m & 7) << 2;                                              \
    f32x4 mxv;                                                                 \
    mxv[0] = Qm[(mr<<8) + ((((s0+0)<<4)+vd) ^ sw2)];                           \
    mxv[1] = Qm[(mr<<8) + ((((s0+1)<<4)+vd) ^ sw2)];                           \
    mxv[2] = Qm[(mr<<8) + ((((s0+2)<<4)+vd) ^ sw2)];                           \
    mxv[3] = Qm[(mr<<8) + ((((s0+3)<<4)+vd) ^ sw2)];                           \
    f32x4 o;                                                                   \
    o[0] = mxv[0]*(VH)[0]; o[1] = mxv[1]*(VH)[1];                              \
    o[2] = mxv[2]*(VH)[2]; o[3] = mxv[3]*(VH)[3];                              \
    __builtin_nontemporal_store(o, (f32x4*)(out + obase + m*256 + c4));        \
} while (0)

#define EPI2(NT, VA, VB) do { EPI1(NT, 0, VA); EPI1(NT, 1, VB); } while (0)

    // ---------------- Phase 2/3: quarter-pipelined, v one phase ahead ----------------
    f32x4 v0, v1, v2, v3, v4, v5, v6, v7;
    VLOAD(0, v0, v1);                 // in flight across the barrier
    BARRIER();                        // Us visible

    f32x4 cA, cB, nA2, nB2;
    CQ(0, cA, cB);
    WRITEQ(cA, cB);
    BARRIER();

    VLOAD(1, v2, v3);
    CQ(1, nA2, nB2);
    EPI2(0, v0, v1);
    BARRIER();
    WRITEQ(nA2, nB2);
    BARRIER();

    VLOAD(2, v4, v5);
    CQ(2, cA, cB);
    EPI2(1, v2, v3);
    BARRIER();
    WRITEQ(cA, cB);
    BARRIER();

    VLOAD(3, v6, v7);
    CQ(3, nA2, nB2);
    EPI2(2, v4, v5);
    BARRIER();
    WRITEQ(nA2, nB2);
    BARRIER();

    EPI2(3, v6, v7);
}

extern "C" void kernel_launch(void* const* d_in, const int* in_sizes, int n_in,
                              void* d_out, int out_size, void* d_ws, size_t ws_size,
                              hipStream_t stream) {
    const float* x       = (const float*)d_in[0];
    const float* norm_w  = (const float*)d_in[1];
    const float* norm_b  = (const float*)d_in[2];
    const float* centers = (const float*)d_in[3];
    const float* spreads = (const float*)d_in[4];
    const float* tbias   = (const float*)d_in[5];
    float* out = (float*)d_out;

    const int nbw = in_sizes[0] / (64 * 512);   // 4096
    hipLaunchKernelGGL(sgating_kernel, dim3(nbw), dim3(512), 0, stream,
                       x, norm_w, norm_b, centers, spreads, tbias, out);
}

// Round 12
// 153.645 us; speedup vs baseline: 1.8957x; 1.8957x over previous
//
#include <hip/hip_runtime.h>
#include <cstdint>

#if __has_builtin(__builtin_amdgcn_exp2f)
#define EXP2F(x) __builtin_amdgcn_exp2f(x)
#else
#define EXP2F(x) exp2f(x)
#endif

typedef _Float16 half8 __attribute__((ext_vector_type(8)));
typedef float    f32x4 __attribute__((ext_vector_type(4)));

// x: (4,1024,64,512) f32; u = x[...,0:256], v = x[...,256:512]
// d = vd*16 + s (head s = d&15); head params hb = s*1024 + w
// score(m,n) = ax*dx + ay*dy - 0.5*(dx^2+dy^2); dx = (n&7)-(m&7), dy = (m>>3)-(n>>3)
// mixed[m,vd,s] = softmax_n(score).Us[n,vd,s]; out = (mixed + bias[w,m]) * v
//
// Round 11 = round 8 EXACTLY (passed, 156 µs), single change: out stores are
// PLAIN (L2 write-back batching) instead of nontemporal. x loads stay plain.
// Bisect of round 10's {NT loads, plain stores} bundle, which hit 128.9 µs
// (= the 805MB/6.25TB/s floor) but diverged post-timing. Also adds a final
// s_waitcnt vmcnt(0) before kernel exit so every out store is complete before
// wave retire (insurance vs the stale-output replay signature).

#define BARRIER() do {                                        \
    asm volatile("s_waitcnt lgkmcnt(0)" ::: "memory");        \
    __builtin_amdgcn_s_barrier();                             \
} while (0)

__global__ __launch_bounds__(512, 4) void sgating_kernel(
    const float* __restrict__ x,
    const float* __restrict__ norm_w,
    const float* __restrict__ norm_b,
    const float* __restrict__ centers,
    const float* __restrict__ spreads,
    const float* __restrict__ tbias,
    float* __restrict__ out)
{
    __shared__ __align__(16) float smem[12288];   // 48 KB: Us 32K + Qm 16K
    _Float16* Us = (_Float16*)smem;
    float*    Qm = smem + 8192;

    const int t     = threadIdx.x;
    const int wv    = t >> 6;
    const int lane  = t & 63;
    const int bw    = blockIdx.x;       // b*1024 + w
    const int w_idx = bw & 1023;
    const size_t xbase = (size_t)bw * (64 * 512);
    const size_t obase = (size_t)bw * (64 * 256);

    // ---------------- Phase 1: load u + LayerNorm -> Us ----------------
    {
        const float4 w4 = *(const float4*)(norm_w + lane * 4);
        const float4 b4 = *(const float4*)(norm_b + lane * 4);
        half8 uar[4];
#pragma unroll
        for (int r = 0; r < 8; ++r) {
            const int n = r * 8 + wv;
            const float4 u = *(const float4*)(x + xbase + (size_t)n * 512 + lane * 4);
            float s  = u.x + u.y + u.z + u.w;
            float sq = u.x*u.x + u.y*u.y + u.z*u.z + u.w*u.w;
#pragma unroll
            for (int off = 1; off < 64; off <<= 1) {
                s  += __shfl_xor(s, off);
                sq += __shfl_xor(sq, off);
            }
            const float mean = s * (1.0f/256.0f);
            const float var  = sq * (1.0f/256.0f) - mean*mean;
            const float rstd = rsqrtf(var + 1e-5f);
            uar[0][r] = (_Float16)((u.x - mean)*rstd*w4.x + b4.x);
            uar[1][r] = (_Float16)((u.y - mean)*rstd*w4.y + b4.y);
            uar[2][r] = (_Float16)((u.z - mean)*rstd*w4.z + b4.z);
            uar[3][r] = (_Float16)((u.w - mean)*rstd*w4.w + b4.w);
        }
        // uar[j][r] = value at n = r*8+wv (q = wv, j-slot = r) -> contiguous b128
#pragma unroll
        for (int j = 0; j < 4; ++j) {
            const int d  = lane * 4 + j;
            const int s  = d & 15;
            const int vd = d >> 4;
            const int qb = wv ^ (vd & 7);
            *(half8*)(Us + (s << 10) + (vd << 6) + (qb << 3)) = uar[j];
        }
    }

    // ---------------- Phase 2 setup ----------------
    const int m16 = lane & 15;
    const int g   = lane >> 4;
    const float LOG2E = 1.4426950408889634f;
    const float C2    = 0.72134752044448f;   // 0.5*log2(e)
    const float mx  = (float)(m16 & 7);
    const float myb = (float)(m16 >> 3);
    const int sA = wv, sB = wv + 8;

    float bias4[4];
#pragma unroll
    for (int nt = 0; nt < 4; ++nt)
        bias4[nt] = tbias[w_idx * 64 + nt * 16 + m16];

    float    exfA[2], exfB[2];
    _Float16 exhA[2], exhB[2];
    half8 EYA_[2], EYB_[2];     // 14-entry f16 ey tables, i -> dy = i-7+myb
    {
        const int hbA = (sA << 10) | w_idx;
        const int hbB = (sB << 10) | w_idx;
        float aq = spreads[hbA]; aq *= aq;
        const float axlA = aq * centers[2*hbA]     * LOG2E;
        const float aylA = aq * centers[2*hbA + 1] * LOG2E;
        aq = spreads[hbB]; aq *= aq;
        const float axlB = aq * centers[2*hbB]     * LOG2E;
        const float aylB = aq * centers[2*hbB + 1] * LOG2E;
#pragma unroll
        for (int kt = 0; kt < 2; ++kt) {
            const float dx = (float)(g + 4*kt) - mx;
            const float eA = EXP2F(dx * fmaf(-C2, dx, axlA));
            const float eB = EXP2F(dx * fmaf(-C2, dx, axlB));
            exfA[kt] = eA; exhA[kt] = (_Float16)eA;
            exfB[kt] = eB; exhB[kt] = (_Float16)eB;
        }
#pragma unroll
        for (int i = 0; i < 16; ++i) {
            const float dy = (float)(i - 7) + myb;
            const _Float16 eA = (i < 14) ? (_Float16)EXP2F(dy * fmaf(-C2, dy, aylA)) : (_Float16)0.f;
            const _Float16 eB = (i < 14) ? (_Float16)EXP2F(dy * fmaf(-C2, dy, aylB)) : (_Float16)0.f;
            if (i < 8) { EYA_[0][i] = eA; EYB_[0][i] = eB; }
            else       { EYA_[1][i-8] = eA; EYB_[1][i-8] = eB; }
        }
    }

#define EYAT(I) ((I) < 8 ? EYA_[0][(I)] : EYA_[1][(I)-8])
#define EYBT(I) ((I) < 8 ? EYB_[0][(I)] : EYB_[1][(I)-8])

#define CQ(NT, vOutA, vOutB) do {                                              \
    f32x4 aA = (f32x4){0.f,0.f,0.f,0.f};                                       \
    f32x4 aB = (f32x4){0.f,0.f,0.f,0.f};                                       \
    half8 eyA8, eyB8;                                                          \
    float syA = 0.f, syB = 0.f;                                                \
    _Pragma("unroll") for (int j = 0; j < 8; ++j) {                            \
        const _Float16 ea = EYAT(2*(NT)+7-j);                                  \
        const _Float16 eb = EYBT(2*(NT)+7-j);                                  \
        eyA8[j] = ea; eyB8[j] = eb;                                            \
        syA += (float)ea; syB += (float)eb;                                    \
    }                                                                          \
    _Pragma("unroll") for (int kt = 0; kt < 2; ++kt) {                         \
        const int qb = (g + 4*kt) ^ (m16 & 7);                                 \
        const half8 uA = *(const half8*)(Us + (sA<<10) + (m16<<6) + (qb<<3));  \
        const half8 uB = *(const half8*)(Us + (sB<<10) + (m16<<6) + (qb<<3));  \
        half8 wA, wB;                                                          \
        _Pragma("unroll") for (int j = 0; j < 8; ++j) {                        \
            wA[j] = eyA8[j] * exhA[kt];                                        \
            wB[j] = eyB8[j] * exhB[kt];                                        \
        }                                                                      \
        aA = __builtin_amdgcn_mfma_f32_16x16x32_f16(uA, wA, aA, 0, 0, 0);      \
        aB = __builtin_amdgcn_mfma_f32_16x16x32_f16(uB, wB, aB, 0, 0, 0);      \
    }                                                                          \
    float rA = (exfA[0] + exfA[1]) * syA;                                      \
    rA += __shfl_xor(rA, 16); rA += __shfl_xor(rA, 32);                        \
    float rB = (exfB[0] + exfB[1]) * syB;                                      \
    rB += __shfl_xor(rB, 16); rB += __shfl_xor(rB, 32);                        \
    const float iA = 1.0f / rA;                                                \
    const float iB = 1.0f / rB;                                                \
    const float bm = bias4[(NT)];                                              \
    _Pragma("unroll") for (int j = 0; j < 4; ++j) {                            \
        vOutA[j] = aA[j]*iA + bm;                                              \
        vOutB[j] = aB[j]*iB + bm;                                              \
    }                                                                          \
} while (0)

#define WRITEQ(vA_, vB_) do {                                                  \
    const int swz = (m16 & 7) << 2;                                            \
    *(f32x4*)(Qm + (m16<<8) + ((sA*16 + g*4) ^ swz)) = vA_;                    \
    *(f32x4*)(Qm + (m16<<8) + ((sB*16 + g*4) ^ swz)) = vB_;                    \
} while (0)

#define VLOAD(NT, V0, V1) do {                                                 \
    V0 = *(const f32x4*)(x + xbase + (size_t)(16*(NT)+wv)*512 + 256 + lane*4); \
    V1 = *(const f32x4*)(x + xbase + (size_t)(16*(NT)+8+wv)*512 + 256 + lane*4);\
} while (0)

#define EPI1(NT, K, VH) do {                                                   \
    const int mr  = wv + 8*(K);                                                \
    const int m   = (NT)*16 + mr;                                              \
    const int c4  = lane * 4;                                                  \
    const int vd  = c4 >> 4;                                                   \
    const int s0  = c4 & 15;                                                   \
    const int sw2 = (m & 7) << 2;                                              \
    f32x4 mxv;                                                                 \
    mxv[0] = Qm[(mr<<8) + ((((s0+0)<<4)+vd) ^ sw2)];                           \
    mxv[1] = Qm[(mr<<8) + ((((s0+1)<<4)+vd) ^ sw2)];                           \
    mxv[2] = Qm[(mr<<8) + ((((s0+2)<<4)+vd) ^ sw2)];                           \
    mxv[3] = Qm[(mr<<8) + ((((s0+3)<<4)+vd) ^ sw2)];                           \
    f32x4 o;                                                                   \
    o[0] = mxv[0]*(VH)[0]; o[1] = mxv[1]*(VH)[1];                              \
    o[2] = mxv[2]*(VH)[2]; o[3] = mxv[3]*(VH)[3];                              \
    *(f32x4*)(out + obase + m*256 + c4) = o;                                   \
} while (0)

#define EPI2(NT, VA, VB) do { EPI1(NT, 0, VA); EPI1(NT, 1, VB); } while (0)

    // ---------------- Phase 2/3: quarter-pipelined, v one phase ahead ----------------
    f32x4 v0, v1, v2, v3, v4, v5, v6, v7;
    VLOAD(0, v0, v1);                 // in flight across the barrier
    BARRIER();                        // Us visible

    f32x4 cA, cB, nA2, nB2;
    CQ(0, cA, cB);
    WRITEQ(cA, cB);
    BARRIER();

    VLOAD(1, v2, v3);
    CQ(1, nA2, nB2);
    EPI2(0, v0, v1);
    BARRIER();
    WRITEQ(nA2, nB2);
    BARRIER();

    VLOAD(2, v4, v5);
    CQ(2, cA, cB);
    EPI2(1, v2, v3);
    BARRIER();
    WRITEQ(cA, cB);
    BARRIER();

    VLOAD(3, v6, v7);
    CQ(3, nA2, nB2);
    EPI2(2, v4, v5);
    BARRIER();
    WRITEQ(nA2, nB2);
    BARRIER();

    EPI2(3, v6, v7);

    // drain all global stores before wave retire (replay-fence insurance)
    asm volatile("s_waitcnt vmcnt(0)" ::: "memory");
}

extern "C" void kernel_launch(void* const* d_in, const int* in_sizes, int n_in,
                              void* d_out, int out_size, void* d_ws, size_t ws_size,
                              hipStream_t stream) {
    const float* x       = (const float*)d_in[0];
    const float* norm_w  = (const float*)d_in[1];
    const float* norm_b  = (const float*)d_in[2];
    const float* centers = (const float*)d_in[3];
    const float* spreads = (const float*)d_in[4];
    const float* tbias   = (const float*)d_in[5];
    float* out = (float*)d_out;

    const int nbw = in_sizes[0] / (64 * 512);   // 4096
    hipLaunchKernelGGL(sgating_kernel, dim3(nbw), dim3(512), 0, stream,
                       x, norm_w, norm_b, centers, spreads, tbias, out);
}

// Round 13
// 128.572 us; speedup vs baseline: 2.2654x; 1.1950x over previous
//
#include <hip/hip_runtime.h>
#include <cstdint>

#if __has_builtin(__builtin_amdgcn_exp2f)
#define EXP2F(x) __builtin_amdgcn_exp2f(x)
#else
#define EXP2F(x) exp2f(x)
#endif

typedef _Float16 half8 __attribute__((ext_vector_type(8)));
typedef float    f32x4 __attribute__((ext_vector_type(4)));

// x: (4,1024,64,512) f32; u = x[...,0:256], v = x[...,256:512]
// d = vd*16 + s (head s = d&15); head params hb = s*1024 + w
// score(m,n) = ax*dx + ay*dy - 0.5*(dx^2+dy^2); dx = (n&7)-(m&7), dy = (m>>3)-(n>>3)
// mixed[m,vd,s] = softmax_n(score).Us[n,vd,s]; out = (mixed + bias[w,m]) * v
//
// Round 12 = round 11 (passed, 153.6 µs: plain stores + final vmcnt drain),
// single change: all x reads are __builtin_nontemporal_load. Mechanism: the
// 512 MB read-once input stream stops thrashing L2/L3, so the caches can
// aggregate/retain the 256 MB output (round 10 showed the combo = 128.9 µs
// = the 805 MB traffic floor). Round 10 lacked the end-of-kernel vmcnt(0)
// drain; this round keeps it (round 11 passed with it).

#define BARRIER() do {                                        \
    asm volatile("s_waitcnt lgkmcnt(0)" ::: "memory");        \
    __builtin_amdgcn_s_barrier();                             \
} while (0)

#define NTLOAD(P) __builtin_nontemporal_load((const f32x4*)(P))

__global__ __launch_bounds__(512, 4) void sgating_kernel(
    const float* __restrict__ x,
    const float* __restrict__ norm_w,
    const float* __restrict__ norm_b,
    const float* __restrict__ centers,
    const float* __restrict__ spreads,
    const float* __restrict__ tbias,
    float* __restrict__ out)
{
    __shared__ __align__(16) float smem[12288];   // 48 KB: Us 32K + Qm 16K
    _Float16* Us = (_Float16*)smem;
    float*    Qm = smem + 8192;

    const int t     = threadIdx.x;
    const int wv    = t >> 6;
    const int lane  = t & 63;
    const int bw    = blockIdx.x;       // b*1024 + w
    const int w_idx = bw & 1023;
    const size_t xbase = (size_t)bw * (64 * 512);
    const size_t obase = (size_t)bw * (64 * 256);

    // ---------------- Phase 1: load u (NT) + LayerNorm -> Us ----------------
    {
        const float4 w4 = *(const float4*)(norm_w + lane * 4);
        const float4 b4 = *(const float4*)(norm_b + lane * 4);
        half8 uar[4];
#pragma unroll
        for (int r = 0; r < 8; ++r) {
            const int n = r * 8 + wv;
            const f32x4 u = NTLOAD(x + xbase + (size_t)n * 512 + lane * 4);
            float s  = u[0] + u[1] + u[2] + u[3];
            float sq = u[0]*u[0] + u[1]*u[1] + u[2]*u[2] + u[3]*u[3];
#pragma unroll
            for (int off = 1; off < 64; off <<= 1) {
                s  += __shfl_xor(s, off);
                sq += __shfl_xor(sq, off);
            }
            const float mean = s * (1.0f/256.0f);
            const float var  = sq * (1.0f/256.0f) - mean*mean;
            const float rstd = rsqrtf(var + 1e-5f);
            uar[0][r] = (_Float16)((u[0] - mean)*rstd*w4.x + b4.x);
            uar[1][r] = (_Float16)((u[1] - mean)*rstd*w4.y + b4.y);
            uar[2][r] = (_Float16)((u[2] - mean)*rstd*w4.z + b4.z);
            uar[3][r] = (_Float16)((u[3] - mean)*rstd*w4.w + b4.w);
        }
        // uar[j][r] = value at n = r*8+wv (q = wv, j-slot = r) -> contiguous b128
#pragma unroll
        for (int j = 0; j < 4; ++j) {
            const int d  = lane * 4 + j;
            const int s  = d & 15;
            const int vd = d >> 4;
            const int qb = wv ^ (vd & 7);
            *(half8*)(Us + (s << 10) + (vd << 6) + (qb << 3)) = uar[j];
        }
    }

    // ---------------- Phase 2 setup ----------------
    const int m16 = lane & 15;
    const int g   = lane >> 4;
    const float LOG2E = 1.4426950408889634f;
    const float C2    = 0.72134752044448f;   // 0.5*log2(e)
    const float mx  = (float)(m16 & 7);
    const float myb = (float)(m16 >> 3);
    const int sA = wv, sB = wv + 8;

    float bias4[4];
#pragma unroll
    for (int nt = 0; nt < 4; ++nt)
        bias4[nt] = tbias[w_idx * 64 + nt * 16 + m16];

    float    exfA[2], exfB[2];
    _Float16 exhA[2], exhB[2];
    half8 EYA_[2], EYB_[2];     // 14-entry f16 ey tables, i -> dy = i-7+myb
    {
        const int hbA = (sA << 10) | w_idx;
        const int hbB = (sB << 10) | w_idx;
        float aq = spreads[hbA]; aq *= aq;
        const float axlA = aq * centers[2*hbA]     * LOG2E;
        const float aylA = aq * centers[2*hbA + 1] * LOG2E;
        aq = spreads[hbB]; aq *= aq;
        const float axlB = aq * centers[2*hbB]     * LOG2E;
        const float aylB = aq * centers[2*hbB + 1] * LOG2E;
#pragma unroll
        for (int kt = 0; kt < 2; ++kt) {
            const float dx = (float)(g + 4*kt) - mx;
            const float eA = EXP2F(dx * fmaf(-C2, dx, axlA));
            const float eB = EXP2F(dx * fmaf(-C2, dx, axlB));
            exfA[kt] = eA; exhA[kt] = (_Float16)eA;
            exfB[kt] = eB; exhB[kt] = (_Float16)eB;
        }
#pragma unroll
        for (int i = 0; i < 16; ++i) {
            const float dy = (float)(i - 7) + myb;
            const _Float16 eA = (i < 14) ? (_Float16)EXP2F(dy * fmaf(-C2, dy, aylA)) : (_Float16)0.f;
            const _Float16 eB = (i < 14) ? (_Float16)EXP2F(dy * fmaf(-C2, dy, aylB)) : (_Float16)0.f;
            if (i < 8) { EYA_[0][i] = eA; EYB_[0][i] = eB; }
            else       { EYA_[1][i-8] = eA; EYB_[1][i-8] = eB; }
        }
    }

#define EYAT(I) ((I) < 8 ? EYA_[0][(I)] : EYA_[1][(I)-8])
#define EYBT(I) ((I) < 8 ? EYB_[0][(I)] : EYB_[1][(I)-8])

#define CQ(NT, vOutA, vOutB) do {                                              \
    f32x4 aA = (f32x4){0.f,0.f,0.f,0.f};                                       \
    f32x4 aB = (f32x4){0.f,0.f,0.f,0.f};                                       \
    half8 eyA8, eyB8;                                                          \
    float syA = 0.f, syB = 0.f;                                                \
    _Pragma("unroll") for (int j = 0; j < 8; ++j) {                            \
        const _Float16 ea = EYAT(2*(NT)+7-j);                                  \
        const _Float16 eb = EYBT(2*(NT)+7-j);                                  \
        eyA8[j] = ea; eyB8[j] = eb;                                            \
        syA += (float)ea; syB += (float)eb;                                    \
    }                                                                          \
    _Pragma("unroll") for (int kt = 0; kt < 2; ++kt) {                         \
        const int qb = (g + 4*kt) ^ (m16 & 7);                                 \
        const half8 uA = *(const half8*)(Us + (sA<<10) + (m16<<6) + (qb<<3));  \
        const half8 uB = *(const half8*)(Us + (sB<<10) + (m16<<6) + (qb<<3));  \
        half8 wA, wB;                                                          \
        _Pragma("unroll") for (int j = 0; j < 8; ++j) {                        \
            wA[j] = eyA8[j] * exhA[kt];                                        \
            wB[j] = eyB8[j] * exhB[kt];                                        \
        }                                                                      \
        aA = __builtin_amdgcn_mfma_f32_16x16x32_f16(uA, wA, aA, 0, 0, 0);      \
        aB = __builtin_amdgcn_mfma_f32_16x16x32_f16(uB, wB, aB, 0, 0, 0);      \
    }                                                                          \
    float rA = (exfA[0] + exfA[1]) * syA;                                      \
    rA += __shfl_xor(rA, 16); rA += __shfl_xor(rA, 32);                        \
    float rB = (exfB[0] + exfB[1]) * syB;                                      \
    rB += __shfl_xor(rB, 16); rB += __shfl_xor(rB, 32);                        \
    const float iA = 1.0f / rA;                                                \
    const float iB = 1.0f / rB;                                                \
    const float bm = bias4[(NT)];                                              \
    _Pragma("unroll") for (int j = 0; j < 4; ++j) {                            \
        vOutA[j] = aA[j]*iA + bm;                                              \
        vOutB[j] = aB[j]*iB + bm;                                              \
    }                                                                          \
} while (0)

#define WRITEQ(vA_, vB_) do {                                                  \
    const int swz = (m16 & 7) << 2;                                            \
    *(f32x4*)(Qm + (m16<<8) + ((sA*16 + g*4) ^ swz)) = vA_;                    \
    *(f32x4*)(Qm + (m16<<8) + ((sB*16 + g*4) ^ swz)) = vB_;                    \
} while (0)

#define VLOAD(NT, V0, V1) do {                                                 \
    V0 = NTLOAD(x + xbase + (size_t)(16*(NT)+wv)*512 + 256 + lane*4);          \
    V1 = NTLOAD(x + xbase + (size_t)(16*(NT)+8+wv)*512 + 256 + lane*4);        \
} while (0)

#define EPI1(NT, K, VH) do {                                                   \
    const int mr  = wv + 8*(K);                                                \
    const int m   = (NT)*16 + mr;                                              \
    const int c4  = lane * 4;                                                  \
    const int vd  = c4 >> 4;                                                   \
    const int s0  = c4 & 15;                                                   \
    const int sw2 = (m & 7) << 2;                                              \
    f32x4 mxv;                                                                 \
    mxv[0] = Qm[(mr<<8) + ((((s0+0)<<4)+vd) ^ sw2)];                           \
    mxv[1] = Qm[(mr<<8) + ((((s0+1)<<4)+vd) ^ sw2)];                           \
    mxv[2] = Qm[(mr<<8) + ((((s0+2)<<4)+vd) ^ sw2)];                           \
    mxv[3] = Qm[(mr<<8) + ((((s0+3)<<4)+vd) ^ sw2)];                           \
    f32x4 o;                                                                   \
    o[0] = mxv[0]*(VH)[0]; o[1] = mxv[1]*(VH)[1];                              \
    o[2] = mxv[2]*(VH)[2]; o[3] = mxv[3]*(VH)[3];                              \
    *(f32x4*)(out + obase + m*256 + c4) = o;                                   \
} while (0)

#define EPI2(NT, VA, VB) do { EPI1(NT, 0, VA); EPI1(NT, 1, VB); } while (0)

    // ---------------- Phase 2/3: quarter-pipelined, v one phase ahead ----------------
    f32x4 v0, v1, v2, v3, v4, v5, v6, v7;
    VLOAD(0, v0, v1);                 // in flight across the barrier
    BARRIER();                        // Us visible

    f32x4 cA, cB, nA2, nB2;
    CQ(0, cA, cB);
    WRITEQ(cA, cB);
    BARRIER();

    VLOAD(1, v2, v3);
    CQ(1, nA2, nB2);
    EPI2(0, v0, v1);
    BARRIER();
    WRITEQ(nA2, nB2);
    BARRIER();

    VLOAD(2, v4, v5);
    CQ(2, cA, cB);
    EPI2(1, v2, v3);
    BARRIER();
    WRITEQ(cA, cB);
    BARRIER();

    VLOAD(3, v6, v7);
    CQ(3, nA2, nB2);
    EPI2(2, v4, v5);
    BARRIER();
    WRITEQ(nA2, nB2);
    BARRIER();

    EPI2(3, v6, v7);

    // drain all global stores before wave retire (replay-fence insurance)
    asm volatile("s_waitcnt vmcnt(0)" ::: "memory");
}

extern "C" void kernel_launch(void* const* d_in, const int* in_sizes, int n_in,
                              void* d_out, int out_size, void* d_ws, size_t ws_size,
                              hipStream_t stream) {
    const float* x       = (const float*)d_in[0];
    const float* norm_w  = (const float*)d_in[1];
    const float* norm_b  = (const float*)d_in[2];
    const float* centers = (const float*)d_in[3];
    const float* spreads = (const float*)d_in[4];
    const float* tbias   = (const float*)d_in[5];
    float* out = (float*)d_out;

    const int nbw = in_sizes[0] / (64 * 512);   // 4096
    hipLaunchKernelGGL(sgating_kernel, dim3(nbw), dim3(512), 0, stream,
                       x, norm_w, norm_b, centers, spreads, tbias, out);
}